// Round 10
// baseline (185.059 us; speedup 1.0000x reference)
//
#include <hip/hip_runtime.h>
#include <stdint.h>

#define SS 4096     // tokens per batch (H*W)
#define CC 64       // channels
#define BB 16       // batch

typedef unsigned short u16;
typedef __attribute__((ext_vector_type(8))) __bf16 bf16x8;
typedef __attribute__((ext_vector_type(8))) short short8;
typedef __attribute__((ext_vector_type(4))) short s16x4;
typedef __attribute__((ext_vector_type(4))) float f32x4;

// pack two f32 -> two bf16 in one u32 (low = a, high = b), round-half-up
__device__ __forceinline__ uint32_t pkbf(float a, float b) {
    uint32_t ua = __float_as_uint(a) + 0x8000u;
    uint32_t ub = __float_as_uint(b) + 0x8000u;
    return __builtin_amdgcn_perm(ub, ua, 0x07060302u);
}

// hardware packed f32x2 -> bf16x2 (RNE), low = a, high = b
__device__ __forceinline__ uint32_t cvtpk(float a, float b) {
    uint32_t r;
    asm("v_cvt_pk_bf16_f32 %0, %1, %2" : "=v"(r) : "v"(a), "v"(b));
    return r;
}

// load 8 consecutive fp32 -> bf16x8 fragment (L2-hot, once/block)
__device__ __forceinline__ bf16x8 ldw8(const float* p) {
    f32x4 lo = *(const f32x4*)(p);
    f32x4 hi = *(const f32x4*)(p + 4);
    union { uint32_t u[4]; bf16x8 v; } r;
    r.u[0] = pkbf(lo[0], lo[1]);
    r.u[1] = pkbf(lo[2], lo[3]);
    r.u[2] = pkbf(hi[0], hi[1]);
    r.u[3] = pkbf(hi[2], hi[3]);
    return r.v;
}

// ---------------------------------------------------------------------------
// Kernel A: QKV projection — R2-verified version, unchanged.
// ---------------------------------------------------------------------------
__global__ __launch_bounds__(256, 4) void qkv_kernel(
    const float* __restrict__ x,
    const float* __restrict__ qw, const float* __restrict__ qb,
    const float* __restrict__ kw, const float* __restrict__ kb,
    const float* __restrict__ vw, const float* __restrict__ vb,
    u16* __restrict__ Q, u16* __restrict__ K, u16* __restrict__ VT)
{
    const int b    = blockIdx.x & 15;          // batch-major for XCD locality
    const int s0   = (blockIdx.x >> 4) << 6;   // 64 s per block
    const int tid  = threadIdx.x;
    const int w    = tid >> 6;
    const int lane = tid & 63;
    const int lq   = lane & 15;
    const int quad = lane >> 4;

    __shared__ u16 wt[3][64 * 72];             // weights bf16 [o][c]
    __shared__ u16 xt[64 * 72];                // x-tile transposed [s][c]; later bounce

    // ---- stage weights bf16 (coalesced 512-B reads, conflict-spread writes) ----
    for (int m = 0; m < 3; ++m) {
        const float* wsrc = (m == 0) ? qw : ((m == 1) ? kw : vw);
#pragma unroll
        for (int i = 0; i < 8; ++i) {
            int p  = tid + (i << 8);           // pair index 0..2047
            int o  = p >> 5;
            int cp = p & 31;
            const float* wp = wsrc + o * 64 + cp * 2;
            ((uint32_t*)&wt[m][o * 72])[cp] = pkbf(wp[0], wp[1]);
        }
    }
    // ---- stage x-tile transposed (reads: 64 consecutive s = 256 B/instr) ----
    {
        const int sl = tid & 63;
        const int g  = tid >> 6;
        const float* xp = x + (size_t)b * CC * SS + s0 + sl;
#pragma unroll
        for (int i = 0; i < 8; ++i) {
            int p = g + (i << 2);              // c-pair 0..31
            float f0 = xp[(size_t)(2 * p) * SS];
            float f1 = xp[(size_t)(2 * p + 1) * SS];
            ((uint32_t*)&xt[sl * 72])[p] = pkbf(f0, f1);
        }
    }
    __syncthreads();

    // A-frags for my 16 s-rows
    bf16x8 a0 = *(const bf16x8*)&xt[(w * 16 + lq) * 72 + quad * 8];
    bf16x8 a1 = *(const bf16x8*)&xt[(w * 16 + lq) * 72 + 32 + quad * 8];
    __syncthreads();                           // xt dead -> reuse as bounce

    u16* bb = xt + w * (16 * 72);              // per-wave bounce

    const float QSCALE = 0.125f * 1.44269504088896340736f;

    for (int m = 0; m < 3; ++m) {
        const float* bsrc = (m == 0) ? qb : ((m == 1) ? kb : vb);
        bf16x8 bfr[2][4];
#pragma unroll
        for (int kc = 0; kc < 2; ++kc)
#pragma unroll
            for (int nt = 0; nt < 4; ++nt)
                bfr[kc][nt] = *(const bf16x8*)&wt[m][(nt * 16 + lq) * 72 + kc * 32 + quad * 8];

        f32x4 acc[4];
#pragma unroll
        for (int nt = 0; nt < 4; ++nt) {
            float bv = bsrc[nt * 16 + lq];
            acc[nt] = (f32x4){bv, bv, bv, bv};
        }
#pragma unroll
        for (int nt = 0; nt < 4; ++nt) {
            acc[nt] = __builtin_amdgcn_mfma_f32_16x16x32_bf16(a0, bfr[0][nt], acc[nt], 0, 0, 0);
            acc[nt] = __builtin_amdgcn_mfma_f32_16x16x32_bf16(a1, bfr[1][nt], acc[nt], 0, 0, 0);
        }

        if (m == 2) {
            // VT[b][c][s]: lane has col c, 4 consecutive s -> 8B store
#pragma unroll
            for (int nt = 0; nt < 4; ++nt) {
                int c = nt * 16 + lq;
                uint2 pv;
                pv.x = pkbf(acc[nt][0], acc[nt][1]);
                pv.y = pkbf(acc[nt][2], acc[nt][3]);
                *(uint2*)(VT + ((size_t)(b * CC + c)) * SS + s0 + w * 16 + quad * 4) = pv;
            }
        } else {
            const float scl = (m == 0) ? QSCALE : 1.0f;
#pragma unroll
            for (int nt = 0; nt < 4; ++nt)
#pragma unroll
                for (int r = 0; r < 4; ++r)
                    bb[(quad * 4 + r) * 72 + nt * 16 + lq] =
                        (u16)((__float_as_uint(acc[nt][r] * scl) + 0x8000u) >> 16);

            const int row = lane >> 2;
            const int ch  = (lane & 3) << 4;
            short8 v0 = *(const short8*)&bb[row * 72 + ch];       // wave-private RAW
            short8 v1 = *(const short8*)&bb[row * 72 + ch + 8];
            u16* dst = ((m == 0) ? Q : K) + ((size_t)(b * SS + s0 + w * 16 + row)) * CC + ch;
            *(short8*)dst = v0;
            *(short8*)(dst + 8) = v1;
        }
    }
}

// ---------------------------------------------------------------------------
// Kernel B: flash attention + fused out-projection.
// V15: 64 q PER WAVE (4 q-groups). Block = 4 waves x 64 q = 256 q; grid =
// 256 = exactly 1 block/CU. Frag ds_reads per iter unchanged per wave but
// serve 2x the q -> per-q DS traffic (the measured 60% pole) halves. At
// 64 q/wave occupancy is structurally 1 wave/SIMD, so __launch_bounds__
// (256,1) lifts the VGPR cap to 512 — the enlarged state (qf[4][2],
// ot[4][4], ~240 VGPR) fits without the R5-R8 spills. All code is the
// R9-verified shape: staging verbatim, per-g QK->softmax->PV body verbatim
// (g-loop bound 2->4), literal indices everywhere. lds_p: one wave-private
// region reused across g (in-wave RAW only).
// ---------------------------------------------------------------------------
__global__ __launch_bounds__(256, 1) void flash_kernel(
    const u16* __restrict__ Q, const u16* __restrict__ K,
    const u16* __restrict__ Vt, const float* __restrict__ ow,
    const float* __restrict__ ob, float* __restrict__ out)
{
    const int b    = blockIdx.x & 15;          // batch-major: XCD gets 2 batches
    const int q0   = (blockIdx.x >> 4) << 8;   // 256 q per block
    const int tid  = threadIdx.x;
    const int w    = tid >> 6;
    const int lane = tid & 63;
    const int lq   = lane & 15;
    const int quad = lane >> 4;

    __shared__ u16 lds_k[2][64 * 64];          // K tile [key][c], chunk-XOR swizzled
    __shared__ u16 lds_v[2][64 * 64];          // V^T tile [c][slot], key-permuted + swizzled
    __shared__ u16 lds_p[4][1024];             // per-wave O bounce (reused across g)

    // Q B-frags: 4 q-groups x 2 kc (wave covers q0 + w*64 .. +63)
    bf16x8 qf[4][2];
#pragma unroll
    for (int g = 0; g < 4; ++g) {
        const u16* qp = Q + ((size_t)(b * SS + q0 + w * 64 + g * 16 + lq)) * CC + quad * 8;
        qf[g][0] = *(const bf16x8*)(qp);
        qf[g][1] = *(const bf16x8*)(qp + 32);
    }

    f32x4 ot[4][4];
#pragma unroll
    for (int g = 0; g < 4; ++g)
#pragma unroll
        for (int ct = 0; ct < 4; ++ct) ot[g][ct] = (f32x4){0.f, 0.f, 0.f, 0.f};
    float lp[4][4];
#pragma unroll
    for (int g = 0; g < 4; ++g)
#pragma unroll
        for (int r = 0; r < 4; ++r) lp[g][r] = 0.f;

    const f32x4 ZV = (f32x4){0.f, 0.f, 0.f, 0.f};   // loop-invariant MFMA C=0

    // staging (R9-verbatim): thread covers row srow, 16B K-chunks 2a, 2a+1
    // (XOR-swizzled); V as 4x 8B pieces at permuted slots.
    const int srow = tid >> 2;
    const int a    = tid & 3;
    const u16* kg = K + ((size_t)(b * SS + srow)) * CC + a * 16;
    const u16* vg = Vt + ((size_t)(b * CC + srow)) * SS + a * 16;
    const int ssw = srow & 7;
    const int sw0 = srow * 64 + ((((a << 1)    ) ^ ssw) << 3);
    const int sw1 = srow * 64 + ((((a << 1) | 1) ^ ssw) << 3);
    const int kcs = (a >> 1) << 2;
    const int us  = (a & 1) << 2;
    const int vw0 = srow * 64 + (((kcs + 0) ^ ssw) << 3) + us;
    const int vw1 = srow * 64 + (((kcs + 1) ^ ssw) << 3) + us;
    const int vw2 = srow * 64 + (((kcs + 2) ^ ssw) << 3) + us;
    const int vw3 = srow * 64 + (((kcs + 3) ^ ssw) << 3) + us;

    {   // prologue: tile 0 -> buf 0
        short8 k0 = *(const short8*)(kg);
        short8 k1 = *(const short8*)(kg + 8);
        union { short8 v; s16x4 h[2]; } v0, v1;
        v0.v = *(const short8*)(vg);
        v1.v = *(const short8*)(vg + 8);
        *(short8*)&lds_k[0][sw0] = k0;
        *(short8*)&lds_k[0][sw1] = k1;
        *(s16x4*)&lds_v[0][vw0] = v0.h[0];
        *(s16x4*)&lds_v[0][vw1] = v0.h[1];
        *(s16x4*)&lds_v[0][vw2] = v1.h[0];
        *(s16x4*)&lds_v[0][vw3] = v1.h[1];
    }

    const int lsw = lq & 7;

    for (int kt = 0; kt < 64; ++kt) {
        __syncthreads();
        const int buf = kt & 1;

        // prefetch tile kt+1 (consumed at end of body)
        const int ktn = (kt + 1) & 63;
        const u16* kgn = kg + (size_t)ktn * (64 * CC);
        const u16* vgn = vg + ktn * 64;
        short8 nk0 = *(const short8*)(kgn);
        short8 nk1 = *(const short8*)(kgn + 8);
        union { short8 v; s16x4 h[2]; } nv0, nv1;
        nv0.v = *(const short8*)(vgn);
        nv1.v = *(const short8*)(vgn + 8);

        // K + V frags loaded ONCE, feed all 4 q-groups
        bf16x8 kf[2][4];
#pragma unroll
        for (int kc = 0; kc < 2; ++kc)
#pragma unroll
            for (int mt = 0; mt < 4; ++mt)
                kf[kc][mt] = *(const bf16x8*)
                    &lds_k[buf][(mt * 16 + lq) * 64 + (((kc << 2) + quad) ^ lsw) * 8];
        bf16x8 vf[2][4];
#pragma unroll
        for (int kc = 0; kc < 2; ++kc)
#pragma unroll
            for (int ct = 0; ct < 4; ++ct)
                vf[kc][ct] = *(const bf16x8*)
                    &lds_v[buf][(ct * 16 + lq) * 64 + (((kc << 2) + quad) ^ lsw) * 8];

        // per q-group: QK -> softmax -> PV (QK of g+1 overlaps VALU of g)
#pragma unroll
        for (int g = 0; g < 4; ++g) {
            f32x4 sa[4];
            __builtin_amdgcn_s_setprio(1);
#pragma unroll
            for (int mt = 0; mt < 4; ++mt) {
                sa[mt] = __builtin_amdgcn_mfma_f32_16x16x32_bf16(
                    kf[0][mt], qf[g][0], ZV, 0, 0, 0);
                sa[mt] = __builtin_amdgcn_mfma_f32_16x16x32_bf16(
                    kf[1][mt], qf[g][1], sa[mt], 0, 0, 0);
            }
            __builtin_amdgcn_s_setprio(0);

            // softmax (fixed max): p = exp2(s); pack straight into PV B-frags
            union { uint32_t u[4]; bf16x8 v; } pf[2];
#pragma unroll
            for (int mt = 0; mt < 4; ++mt) {
                float p0 = __builtin_amdgcn_exp2f(sa[mt][0]);
                float p1 = __builtin_amdgcn_exp2f(sa[mt][1]);
                float p2 = __builtin_amdgcn_exp2f(sa[mt][2]);
                float p3 = __builtin_amdgcn_exp2f(sa[mt][3]);
                lp[g][0] += p0; lp[g][1] += p1; lp[g][2] += p2; lp[g][3] += p3;
                pf[mt >> 1].u[(mt & 1) * 2 + 0] = cvtpk(p0, p1);
                pf[mt >> 1].u[(mt & 1) * 2 + 1] = cvtpk(p2, p3);
            }

            // O^T += V^T * P^T
            __builtin_amdgcn_s_setprio(1);
#pragma unroll
            for (int kc = 0; kc < 2; ++kc)
#pragma unroll
                for (int ct = 0; ct < 4; ++ct)
                    ot[g][ct] = __builtin_amdgcn_mfma_f32_16x16x32_bf16(
                        vf[kc][ct], pf[kc].v, ot[g][ct], 0, 0, 0);
            __builtin_amdgcn_s_setprio(0);
        }

        // stage prefetched tile into other buffer
        u16* lkd = lds_k[buf ^ 1];
        u16* lvd = lds_v[buf ^ 1];
        *(short8*)&lkd[sw0] = nk0;
        *(short8*)&lkd[sw1] = nk1;
        *(s16x4*)&lvd[vw0] = nv0.h[0];
        *(s16x4*)&lvd[vw1] = nv0.h[1];
        *(s16x4*)&lvd[vw2] = nv1.h[0];
        *(s16x4*)&lvd[vw3] = nv1.h[1];
    }

    // ---- fused out-projection epilogue (per-g, wave-private bounce) ----
    bf16x8 wf[2][4];
#pragma unroll
    for (int kc = 0; kc < 2; ++kc)
#pragma unroll
        for (int nt = 0; nt < 4; ++nt)
            wf[kc][nt] = ldw8(ow + (nt * 16 + lq) * 64 + kc * 32 + quad * 8);
    float bias[4];
#pragma unroll
    for (int nt = 0; nt < 4; ++nt) bias[nt] = ob[nt * 16 + lq];

    u16* po = lds_p[w];                        // wave-private, reused across g

#pragma unroll
    for (int g = 0; g < 4; ++g) {
        float l = (lp[g][0] + lp[g][1]) + (lp[g][2] + lp[g][3]);
        l += __shfl_xor(l, 16);
        l += __shfl_xor(l, 32);
        const float inv = 1.0f / l;

#pragma unroll
        for (int ct = 0; ct < 4; ++ct) {
            uint2 pv;
            pv.x = pkbf(ot[g][ct][0] * inv, ot[g][ct][1] * inv);
            pv.y = pkbf(ot[g][ct][2] * inv, ot[g][ct][3] * inv);
            *(uint2*)&po[lq * 64 + (((ct * 2 + (quad >> 1)) ^ lsw) << 3) + (quad & 1) * 4] = pv;
        }
        bf16x8 oa0 = *(const bf16x8*)&po[lq * 64 + (((0 * 4 + quad) ^ lsw) << 3)];
        bf16x8 oa1 = *(const bf16x8*)&po[lq * 64 + (((1 * 4 + quad) ^ lsw) << 3)];

        f32x4 acc[4];
#pragma unroll
        for (int nt = 0; nt < 4; ++nt)
            acc[nt] = (f32x4){bias[nt], bias[nt], bias[nt], bias[nt]};
#pragma unroll
        for (int nt = 0; nt < 4; ++nt) {
            acc[nt] = __builtin_amdgcn_mfma_f32_16x16x32_bf16(oa0, wf[0][nt], acc[nt], 0, 0, 0);
            acc[nt] = __builtin_amdgcn_mfma_f32_16x16x32_bf16(oa1, wf[1][nt], acc[nt], 0, 0, 0);
        }
#pragma unroll
        for (int nt = 0; nt < 4; ++nt) {
            float* dst = out + ((size_t)(b * CC + nt * 16 + lq)) * SS
                       + q0 + w * 64 + g * 16 + quad * 4;
            *(f32x4*)dst = acc[nt];
        }
    }
}

// ---------------------------------------------------------------------------
extern "C" void kernel_launch(void* const* d_in, const int* in_sizes, int n_in,
                              void* d_out, int out_size, void* d_ws, size_t ws_size,
                              hipStream_t stream)
{
    const float* x  = (const float*)d_in[0];
    const float* qw = (const float*)d_in[1];
    const float* qb = (const float*)d_in[2];
    const float* kw = (const float*)d_in[3];
    const float* kb = (const float*)d_in[4];
    const float* vw = (const float*)d_in[5];
    const float* vb = (const float*)d_in[6];
    const float* ow = (const float*)d_in[7];
    const float* ob = (const float*)d_in[8];
    float* out = (float*)d_out;

    const size_t T = (size_t)BB * SS * CC;
    u16* Q  = (u16*)d_ws;
    u16* K  = Q + T;
    u16* VT = K + T;

    qkv_kernel<<<dim3(BB * 64), dim3(256), 0, stream>>>(x, qw, qb, kw, kb, vw, vb, Q, K, VT);
    flash_kernel<<<dim3(BB * 16), dim3(256), 0, stream>>>(Q, K, VT, ow, ob, out);
}

// Round 11
// 165.455 us; speedup vs baseline: 1.1185x; 1.1185x over previous
//
#include <hip/hip_runtime.h>
#include <stdint.h>

#define SS 4096     // tokens per batch (H*W)
#define CC 64       // channels
#define BB 16       // batch

typedef unsigned short u16;
typedef __attribute__((ext_vector_type(8))) __bf16 bf16x8;
typedef __attribute__((ext_vector_type(8))) short short8;
typedef __attribute__((ext_vector_type(4))) short s16x4;
typedef __attribute__((ext_vector_type(4))) float f32x4;

// pack two f32 -> two bf16 in one u32 (low = a, high = b), round-half-up
__device__ __forceinline__ uint32_t pkbf(float a, float b) {
    uint32_t ua = __float_as_uint(a) + 0x8000u;
    uint32_t ub = __float_as_uint(b) + 0x8000u;
    return __builtin_amdgcn_perm(ub, ua, 0x07060302u);
}

// hardware packed f32x2 -> bf16x2 (RNE), low = a, high = b
__device__ __forceinline__ uint32_t cvtpk(float a, float b) {
    uint32_t r;
    asm("v_cvt_pk_bf16_f32 %0, %1, %2" : "=v"(r) : "v"(a), "v"(b));
    return r;
}

// load 8 consecutive fp32 -> bf16x8 fragment (L2-hot, once/block)
__device__ __forceinline__ bf16x8 ldw8(const float* p) {
    f32x4 lo = *(const f32x4*)(p);
    f32x4 hi = *(const f32x4*)(p + 4);
    union { uint32_t u[4]; bf16x8 v; } r;
    r.u[0] = pkbf(lo[0], lo[1]);
    r.u[1] = pkbf(lo[2], lo[3]);
    r.u[2] = pkbf(hi[0], hi[1]);
    r.u[3] = pkbf(hi[2], hi[3]);
    return r.v;
}

// ---------------------------------------------------------------------------
// Kernel A: QKV projection — R2-verified version, unchanged.
// ---------------------------------------------------------------------------
__global__ __launch_bounds__(256, 4) void qkv_kernel(
    const float* __restrict__ x,
    const float* __restrict__ qw, const float* __restrict__ qb,
    const float* __restrict__ kw, const float* __restrict__ kb,
    const float* __restrict__ vw, const float* __restrict__ vb,
    u16* __restrict__ Q, u16* __restrict__ K, u16* __restrict__ VT)
{
    const int b    = blockIdx.x & 15;          // batch-major for XCD locality
    const int s0   = (blockIdx.x >> 4) << 6;   // 64 s per block
    const int tid  = threadIdx.x;
    const int w    = tid >> 6;
    const int lane = tid & 63;
    const int lq   = lane & 15;
    const int quad = lane >> 4;

    __shared__ u16 wt[3][64 * 72];             // weights bf16 [o][c]
    __shared__ u16 xt[64 * 72];                // x-tile transposed [s][c]; later bounce

    // ---- stage weights bf16 (coalesced 512-B reads, conflict-spread writes) ----
    for (int m = 0; m < 3; ++m) {
        const float* wsrc = (m == 0) ? qw : ((m == 1) ? kw : vw);
#pragma unroll
        for (int i = 0; i < 8; ++i) {
            int p  = tid + (i << 8);           // pair index 0..2047
            int o  = p >> 5;
            int cp = p & 31;
            const float* wp = wsrc + o * 64 + cp * 2;
            ((uint32_t*)&wt[m][o * 72])[cp] = pkbf(wp[0], wp[1]);
        }
    }
    // ---- stage x-tile transposed (reads: 64 consecutive s = 256 B/instr) ----
    {
        const int sl = tid & 63;
        const int g  = tid >> 6;
        const float* xp = x + (size_t)b * CC * SS + s0 + sl;
#pragma unroll
        for (int i = 0; i < 8; ++i) {
            int p = g + (i << 2);              // c-pair 0..31
            float f0 = xp[(size_t)(2 * p) * SS];
            float f1 = xp[(size_t)(2 * p + 1) * SS];
            ((uint32_t*)&xt[sl * 72])[p] = pkbf(f0, f1);
        }
    }
    __syncthreads();

    // A-frags for my 16 s-rows
    bf16x8 a0 = *(const bf16x8*)&xt[(w * 16 + lq) * 72 + quad * 8];
    bf16x8 a1 = *(const bf16x8*)&xt[(w * 16 + lq) * 72 + 32 + quad * 8];
    __syncthreads();                           // xt dead -> reuse as bounce

    u16* bb = xt + w * (16 * 72);              // per-wave bounce

    const float QSCALE = 0.125f * 1.44269504088896340736f;

    for (int m = 0; m < 3; ++m) {
        const float* bsrc = (m == 0) ? qb : ((m == 1) ? kb : vb);
        bf16x8 bfr[2][4];
#pragma unroll
        for (int kc = 0; kc < 2; ++kc)
#pragma unroll
            for (int nt = 0; nt < 4; ++nt)
                bfr[kc][nt] = *(const bf16x8*)&wt[m][(nt * 16 + lq) * 72 + kc * 32 + quad * 8];

        f32x4 acc[4];
#pragma unroll
        for (int nt = 0; nt < 4; ++nt) {
            float bv = bsrc[nt * 16 + lq];
            acc[nt] = (f32x4){bv, bv, bv, bv};
        }
#pragma unroll
        for (int nt = 0; nt < 4; ++nt) {
            acc[nt] = __builtin_amdgcn_mfma_f32_16x16x32_bf16(a0, bfr[0][nt], acc[nt], 0, 0, 0);
            acc[nt] = __builtin_amdgcn_mfma_f32_16x16x32_bf16(a1, bfr[1][nt], acc[nt], 0, 0, 0);
        }

        if (m == 2) {
            // VT[b][c][s]: lane has col c, 4 consecutive s -> 8B store
#pragma unroll
            for (int nt = 0; nt < 4; ++nt) {
                int c = nt * 16 + lq;
                uint2 pv;
                pv.x = pkbf(acc[nt][0], acc[nt][1]);
                pv.y = pkbf(acc[nt][2], acc[nt][3]);
                *(uint2*)(VT + ((size_t)(b * CC + c)) * SS + s0 + w * 16 + quad * 4) = pv;
            }
        } else {
            const float scl = (m == 0) ? QSCALE : 1.0f;
#pragma unroll
            for (int nt = 0; nt < 4; ++nt)
#pragma unroll
                for (int r = 0; r < 4; ++r)
                    bb[(quad * 4 + r) * 72 + nt * 16 + lq] =
                        (u16)((__float_as_uint(acc[nt][r] * scl) + 0x8000u) >> 16);

            const int row = lane >> 2;
            const int ch  = (lane & 3) << 4;
            short8 v0 = *(const short8*)&bb[row * 72 + ch];       // wave-private RAW
            short8 v1 = *(const short8*)&bb[row * 72 + ch + 8];
            u16* dst = ((m == 0) ? Q : K) + ((size_t)(b * SS + s0 + w * 16 + row)) * CC + ch;
            *(short8*)dst = v0;
            *(short8*)(dst + 8) = v1;
        }
    }
}

// ---------------------------------------------------------------------------
// Kernel B: flash attention + fused out-projection.
// V16 = R9 (2 q-groups/wave, 2 blocks/CU — the verified 85.5us structure)
// with TWO 64-key tiles per barrier: quad-buffered K/V (4x8KB each), 32
// loop iterations, half the barrier/drain events. Body code is R9-verbatim
// instantiated per sub-tile with literal buffer indices; prefetch of the
// next tile PAIR is issued at the top and covered by the full 2-tile body.
// Epilogue bounce is wave-private (R10-verified pattern), 8KB. LDS total
// 72KB -> still 2 blocks/CU. R10's 64q/wave (1 wave/SIMD) is refuted:
// TLP at 2 waves/SIMD is load-bearing.
// ---------------------------------------------------------------------------
__global__ __launch_bounds__(256, 2) void flash_kernel(
    const u16* __restrict__ Q, const u16* __restrict__ K,
    const u16* __restrict__ Vt, const float* __restrict__ ow,
    const float* __restrict__ ob, float* __restrict__ out)
{
    const int b    = blockIdx.x & 15;          // batch-major: XCD gets 2 batches
    const int q0   = (blockIdx.x >> 4) << 7;   // 128 q per block
    const int tid  = threadIdx.x;
    const int w    = tid >> 6;
    const int lane = tid & 63;
    const int lq   = lane & 15;
    const int quad = lane >> 4;

    __shared__ u16 lds_k[4][64 * 64];          // K tiles, chunk-XOR swizzled (quad-buf)
    __shared__ u16 lds_v[4][64 * 64];          // V^T tiles, key-permuted + swizzled
    __shared__ u16 lds_p[4][1024];             // per-wave epilogue O bounce

    // Q B-frags for both groups
    bf16x8 qf[2][2];
#pragma unroll
    for (int g = 0; g < 2; ++g) {
        const u16* qp = Q + ((size_t)(b * SS + q0 + g * 64 + w * 16 + lq)) * CC + quad * 8;
        qf[g][0] = *(const bf16x8*)(qp);
        qf[g][1] = *(const bf16x8*)(qp + 32);
    }

    f32x4 ot[2][4];
#pragma unroll
    for (int g = 0; g < 2; ++g)
#pragma unroll
        for (int ct = 0; ct < 4; ++ct) ot[g][ct] = (f32x4){0.f, 0.f, 0.f, 0.f};
    float lp[2][4] = {{0.f, 0.f, 0.f, 0.f}, {0.f, 0.f, 0.f, 0.f}};

    const f32x4 ZV = (f32x4){0.f, 0.f, 0.f, 0.f};   // loop-invariant MFMA C=0

    // staging (R9-verbatim): thread covers row srow, 16B K-chunks 2a, 2a+1
    // (XOR-swizzled); V as 4x 8B pieces at permuted slots.
    const int srow = tid >> 2;
    const int a    = tid & 3;
    const u16* kg = K + ((size_t)(b * SS + srow)) * CC + a * 16;
    const u16* vg = Vt + ((size_t)(b * CC + srow)) * SS + a * 16;
    const int ssw = srow & 7;
    const int sw0 = srow * 64 + ((((a << 1)    ) ^ ssw) << 3);
    const int sw1 = srow * 64 + ((((a << 1) | 1) ^ ssw) << 3);
    const int kcs = (a >> 1) << 2;
    const int us  = (a & 1) << 2;
    const int vw0 = srow * 64 + (((kcs + 0) ^ ssw) << 3) + us;
    const int vw1 = srow * 64 + (((kcs + 1) ^ ssw) << 3) + us;
    const int vw2 = srow * 64 + (((kcs + 2) ^ ssw) << 3) + us;
    const int vw3 = srow * 64 + (((kcs + 3) ^ ssw) << 3) + us;

// stage one tile (K regs k0_,k1_; V union regs v0_,v1_) into buffer BUF
#define STAGE(BUF, K0_, K1_, V0_, V1_) do {                                   \
    *(short8*)&lds_k[BUF][sw0] = K0_;                                         \
    *(short8*)&lds_k[BUF][sw1] = K1_;                                         \
    *(s16x4*)&lds_v[BUF][vw0] = V0_.h[0];                                     \
    *(s16x4*)&lds_v[BUF][vw1] = V0_.h[1];                                     \
    *(s16x4*)&lds_v[BUF][vw2] = V1_.h[0];                                     \
    *(s16x4*)&lds_v[BUF][vw3] = V1_.h[1];                                     \
} while (0)

    {   // prologue: tiles 0,1 -> bufs 0,1
        short8 k0a = *(const short8*)(kg);
        short8 k1a = *(const short8*)(kg + 8);
        union { short8 v; s16x4 h[2]; } v0a, v1a;
        v0a.v = *(const short8*)(vg);
        v1a.v = *(const short8*)(vg + 8);
        const u16* kg1 = kg + (size_t)(64 * CC);
        const u16* vg1 = vg + 64;
        short8 k0b = *(const short8*)(kg1);
        short8 k1b = *(const short8*)(kg1 + 8);
        union { short8 v; s16x4 h[2]; } v0b, v1b;
        v0b.v = *(const short8*)(vg1);
        v1b.v = *(const short8*)(vg1 + 8);
        STAGE(0, k0a, k1a, v0a, v1a);
        STAGE(1, k0b, k1b, v0b, v1b);
    }

    const int lsw = lq & 7;

// one 64-key sub-tile from buffer BUF (R9 body verbatim, literal BUF)
#define SUBTILE(BUF) do {                                                     \
    bf16x8 kf[2][4];                                                          \
    _Pragma("unroll")                                                         \
    for (int kc = 0; kc < 2; ++kc)                                            \
        _Pragma("unroll")                                                     \
        for (int mt = 0; mt < 4; ++mt)                                        \
            kf[kc][mt] = *(const bf16x8*)                                     \
                &lds_k[BUF][(mt * 16 + lq) * 64 + (((kc << 2) + quad) ^ lsw) * 8]; \
    f32x4 sa[2][4];                                                           \
    __builtin_amdgcn_s_setprio(1);                                            \
    _Pragma("unroll")                                                         \
    for (int g = 0; g < 2; ++g)                                               \
        _Pragma("unroll")                                                     \
        for (int mt = 0; mt < 4; ++mt) {                                      \
            sa[g][mt] = __builtin_amdgcn_mfma_f32_16x16x32_bf16(              \
                kf[0][mt], qf[g][0], ZV, 0, 0, 0);                            \
            sa[g][mt] = __builtin_amdgcn_mfma_f32_16x16x32_bf16(              \
                kf[1][mt], qf[g][1], sa[g][mt], 0, 0, 0);                     \
        }                                                                     \
    __builtin_amdgcn_s_setprio(0);                                            \
    bf16x8 vf[2][4];                                                          \
    _Pragma("unroll")                                                         \
    for (int kc = 0; kc < 2; ++kc)                                            \
        _Pragma("unroll")                                                     \
        for (int ct = 0; ct < 4; ++ct)                                        \
            vf[kc][ct] = *(const bf16x8*)                                     \
                &lds_v[BUF][(ct * 16 + lq) * 64 + (((kc << 2) + quad) ^ lsw) * 8]; \
    _Pragma("unroll")                                                         \
    for (int g = 0; g < 2; ++g) {                                             \
        union { uint32_t u[4]; bf16x8 v; } pf[2];                             \
        _Pragma("unroll")                                                     \
        for (int mt = 0; mt < 4; ++mt) {                                      \
            float p0 = __builtin_amdgcn_exp2f(sa[g][mt][0]);                  \
            float p1 = __builtin_amdgcn_exp2f(sa[g][mt][1]);                  \
            float p2 = __builtin_amdgcn_exp2f(sa[g][mt][2]);                  \
            float p3 = __builtin_amdgcn_exp2f(sa[g][mt][3]);                  \
            lp[g][0] += p0; lp[g][1] += p1; lp[g][2] += p2; lp[g][3] += p3;   \
            pf[mt >> 1].u[(mt & 1) * 2 + 0] = cvtpk(p0, p1);                  \
            pf[mt >> 1].u[(mt & 1) * 2 + 1] = cvtpk(p2, p3);                  \
        }                                                                     \
        __builtin_amdgcn_s_setprio(1);                                        \
        _Pragma("unroll")                                                     \
        for (int kc = 0; kc < 2; ++kc)                                        \
            _Pragma("unroll")                                                 \
            for (int ct = 0; ct < 4; ++ct)                                    \
                ot[g][ct] = __builtin_amdgcn_mfma_f32_16x16x32_bf16(          \
                    vf[kc][ct], pf[kc].v, ot[g][ct], 0, 0, 0);                \
        __builtin_amdgcn_s_setprio(0);                                        \
    }                                                                         \
} while (0)

    for (int it = 0; it < 32; ++it) {
        __syncthreads();
        const int pr = it & 1;                 // 0: compute bufs {0,1}, 1: {2,3}

        // prefetch next tile PAIR (tiles 2it+2, 2it+3; dummy wrap at end)
        const int kt0 = (2 * it + 2) & 63;
        const int kt1 = (2 * it + 3) & 63;
        const u16* kga = kg + (size_t)kt0 * (64 * CC);
        const u16* vga = vg + kt0 * 64;
        const u16* kgb = kg + (size_t)kt1 * (64 * CC);
        const u16* vgb = vg + kt1 * 64;
        short8 nk0a = *(const short8*)(kga);
        short8 nk1a = *(const short8*)(kga + 8);
        union { short8 v; s16x4 h[2]; } nv0a, nv1a;
        nv0a.v = *(const short8*)(vga);
        nv1a.v = *(const short8*)(vga + 8);
        short8 nk0b = *(const short8*)(kgb);
        short8 nk1b = *(const short8*)(kgb + 8);
        union { short8 v; s16x4 h[2]; } nv0b, nv1b;
        nv0b.v = *(const short8*)(vgb);
        nv1b.v = *(const short8*)(vgb + 8);

        if (pr == 0) { SUBTILE(0); SUBTILE(1); }
        else         { SUBTILE(2); SUBTILE(3); }

        // stage prefetched pair into the other buffer pair
        if (pr == 0) {
            STAGE(2, nk0a, nk1a, nv0a, nv1a);
            STAGE(3, nk0b, nk1b, nv0b, nv1b);
        } else {
            STAGE(0, nk0a, nk1a, nv0a, nv1a);
            STAGE(1, nk0b, nk1b, nv0b, nv1b);
        }
    }
#undef SUBTILE
#undef STAGE

    // ---- fused out-projection epilogue (wave-private bounce) ----
    bf16x8 wf[2][4];
#pragma unroll
    for (int kc = 0; kc < 2; ++kc)
#pragma unroll
        for (int nt = 0; nt < 4; ++nt)
            wf[kc][nt] = ldw8(ow + (nt * 16 + lq) * 64 + kc * 32 + quad * 8);
    float bias[4];
#pragma unroll
    for (int nt = 0; nt < 4; ++nt) bias[nt] = ob[nt * 16 + lq];

    u16* po = lds_p[w];                        // wave-private, reused across g

#pragma unroll
    for (int g = 0; g < 2; ++g) {
        float l = (lp[g][0] + lp[g][1]) + (lp[g][2] + lp[g][3]);
        l += __shfl_xor(l, 16);
        l += __shfl_xor(l, 32);
        const float inv = 1.0f / l;

#pragma unroll
        for (int ct = 0; ct < 4; ++ct) {
            uint2 pv;
            pv.x = pkbf(ot[g][ct][0] * inv, ot[g][ct][1] * inv);
            pv.y = pkbf(ot[g][ct][2] * inv, ot[g][ct][3] * inv);
            *(uint2*)&po[lq * 64 + (((ct * 2 + (quad >> 1)) ^ lsw) << 3) + (quad & 1) * 4] = pv;
        }
        bf16x8 oa0 = *(const bf16x8*)&po[lq * 64 + (((0 * 4 + quad) ^ lsw) << 3)];
        bf16x8 oa1 = *(const bf16x8*)&po[lq * 64 + (((1 * 4 + quad) ^ lsw) << 3)];

        f32x4 acc[4];
#pragma unroll
        for (int nt = 0; nt < 4; ++nt)
            acc[nt] = (f32x4){bias[nt], bias[nt], bias[nt], bias[nt]};
#pragma unroll
        for (int nt = 0; nt < 4; ++nt) {
            acc[nt] = __builtin_amdgcn_mfma_f32_16x16x32_bf16(oa0, wf[0][nt], acc[nt], 0, 0, 0);
            acc[nt] = __builtin_amdgcn_mfma_f32_16x16x32_bf16(oa1, wf[1][nt], acc[nt], 0, 0, 0);
        }
#pragma unroll
        for (int nt = 0; nt < 4; ++nt) {
            float* dst = out + ((size_t)(b * CC + nt * 16 + lq)) * SS
                       + q0 + g * 64 + w * 16 + quad * 4;
            *(f32x4*)dst = acc[nt];
        }
    }
}

// ---------------------------------------------------------------------------
extern "C" void kernel_launch(void* const* d_in, const int* in_sizes, int n_in,
                              void* d_out, int out_size, void* d_ws, size_t ws_size,
                              hipStream_t stream)
{
    const float* x  = (const float*)d_in[0];
    const float* qw = (const float*)d_in[1];
    const float* qb = (const float*)d_in[2];
    const float* kw = (const float*)d_in[3];
    const float* kb = (const float*)d_in[4];
    const float* vw = (const float*)d_in[5];
    const float* vb = (const float*)d_in[6];
    const float* ow = (const float*)d_in[7];
    const float* ob = (const float*)d_in[8];
    float* out = (float*)d_out;

    const size_t T = (size_t)BB * SS * CC;
    u16* Q  = (u16*)d_ws;
    u16* K  = Q + T;
    u16* VT = K + T;

    qkv_kernel<<<dim3(BB * 64), dim3(256), 0, stream>>>(x, qw, qb, kw, kb, vw, vb, Q, K, VT);
    flash_kernel<<<dim3(BB * 32), dim3(256), 0, stream>>>(Q, K, VT, ow, ob, out);
}

// Round 12
// 163.074 us; speedup vs baseline: 1.1348x; 1.0146x over previous
//
#include <hip/hip_runtime.h>
#include <stdint.h>

#define SS 4096     // tokens per batch (H*W)
#define CC 64       // channels
#define BB 16       // batch

typedef unsigned short u16;
typedef __attribute__((ext_vector_type(8))) __bf16 bf16x8;
typedef __attribute__((ext_vector_type(8))) short short8;
typedef __attribute__((ext_vector_type(4))) short s16x4;
typedef __attribute__((ext_vector_type(4))) float f32x4;

// pack two f32 -> two bf16 in one u32 (low = a, high = b), round-half-up
__device__ __forceinline__ uint32_t pkbf(float a, float b) {
    uint32_t ua = __float_as_uint(a) + 0x8000u;
    uint32_t ub = __float_as_uint(b) + 0x8000u;
    return __builtin_amdgcn_perm(ub, ua, 0x07060302u);
}

// hardware packed f32x2 -> bf16x2 (RNE), low = a, high = b
__device__ __forceinline__ uint32_t cvtpk(float a, float b) {
    uint32_t r;
    asm("v_cvt_pk_bf16_f32 %0, %1, %2" : "=v"(r) : "v"(a), "v"(b));
    return r;
}

// load 8 consecutive fp32 -> bf16x8 fragment (L2-hot, once/block)
__device__ __forceinline__ bf16x8 ldw8(const float* p) {
    f32x4 lo = *(const f32x4*)(p);
    f32x4 hi = *(const f32x4*)(p + 4);
    union { uint32_t u[4]; bf16x8 v; } r;
    r.u[0] = pkbf(lo[0], lo[1]);
    r.u[1] = pkbf(lo[2], lo[3]);
    r.u[2] = pkbf(hi[0], hi[1]);
    r.u[3] = pkbf(hi[2], hi[3]);
    return r.v;
}

// ---------------------------------------------------------------------------
// Kernel A: QKV projection — R2-verified version, unchanged.
// ---------------------------------------------------------------------------
__global__ __launch_bounds__(256, 4) void qkv_kernel(
    const float* __restrict__ x,
    const float* __restrict__ qw, const float* __restrict__ qb,
    const float* __restrict__ kw, const float* __restrict__ kb,
    const float* __restrict__ vw, const float* __restrict__ vb,
    u16* __restrict__ Q, u16* __restrict__ K, u16* __restrict__ VT)
{
    const int b    = blockIdx.x & 15;          // batch-major for XCD locality
    const int s0   = (blockIdx.x >> 4) << 6;   // 64 s per block
    const int tid  = threadIdx.x;
    const int w    = tid >> 6;
    const int lane = tid & 63;
    const int lq   = lane & 15;
    const int quad = lane >> 4;

    __shared__ u16 wt[3][64 * 72];             // weights bf16 [o][c]
    __shared__ u16 xt[64 * 72];                // x-tile transposed [s][c]; later bounce

    // ---- stage weights bf16 (coalesced 512-B reads, conflict-spread writes) ----
    for (int m = 0; m < 3; ++m) {
        const float* wsrc = (m == 0) ? qw : ((m == 1) ? kw : vw);
#pragma unroll
        for (int i = 0; i < 8; ++i) {
            int p  = tid + (i << 8);           // pair index 0..2047
            int o  = p >> 5;
            int cp = p & 31;
            const float* wp = wsrc + o * 64 + cp * 2;
            ((uint32_t*)&wt[m][o * 72])[cp] = pkbf(wp[0], wp[1]);
        }
    }
    // ---- stage x-tile transposed (reads: 64 consecutive s = 256 B/instr) ----
    {
        const int sl = tid & 63;
        const int g  = tid >> 6;
        const float* xp = x + (size_t)b * CC * SS + s0 + sl;
#pragma unroll
        for (int i = 0; i < 8; ++i) {
            int p = g + (i << 2);              // c-pair 0..31
            float f0 = xp[(size_t)(2 * p) * SS];
            float f1 = xp[(size_t)(2 * p + 1) * SS];
            ((uint32_t*)&xt[sl * 72])[p] = pkbf(f0, f1);
        }
    }
    __syncthreads();

    // A-frags for my 16 s-rows
    bf16x8 a0 = *(const bf16x8*)&xt[(w * 16 + lq) * 72 + quad * 8];
    bf16x8 a1 = *(const bf16x8*)&xt[(w * 16 + lq) * 72 + 32 + quad * 8];
    __syncthreads();                           // xt dead -> reuse as bounce

    u16* bb = xt + w * (16 * 72);              // per-wave bounce

    const float QSCALE = 0.125f * 1.44269504088896340736f;

    for (int m = 0; m < 3; ++m) {
        const float* bsrc = (m == 0) ? qb : ((m == 1) ? kb : vb);
        bf16x8 bfr[2][4];
#pragma unroll
        for (int kc = 0; kc < 2; ++kc)
#pragma unroll
            for (int nt = 0; nt < 4; ++nt)
                bfr[kc][nt] = *(const bf16x8*)&wt[m][(nt * 16 + lq) * 72 + kc * 32 + quad * 8];

        f32x4 acc[4];
#pragma unroll
        for (int nt = 0; nt < 4; ++nt) {
            float bv = bsrc[nt * 16 + lq];
            acc[nt] = (f32x4){bv, bv, bv, bv};
        }
#pragma unroll
        for (int nt = 0; nt < 4; ++nt) {
            acc[nt] = __builtin_amdgcn_mfma_f32_16x16x32_bf16(a0, bfr[0][nt], acc[nt], 0, 0, 0);
            acc[nt] = __builtin_amdgcn_mfma_f32_16x16x32_bf16(a1, bfr[1][nt], acc[nt], 0, 0, 0);
        }

        if (m == 2) {
            // VT[b][c][s]: lane has col c, 4 consecutive s -> 8B store
#pragma unroll
            for (int nt = 0; nt < 4; ++nt) {
                int c = nt * 16 + lq;
                uint2 pv;
                pv.x = pkbf(acc[nt][0], acc[nt][1]);
                pv.y = pkbf(acc[nt][2], acc[nt][3]);
                *(uint2*)(VT + ((size_t)(b * CC + c)) * SS + s0 + w * 16 + quad * 4) = pv;
            }
        } else {
            const float scl = (m == 0) ? QSCALE : 1.0f;
#pragma unroll
            for (int nt = 0; nt < 4; ++nt)
#pragma unroll
                for (int r = 0; r < 4; ++r)
                    bb[(quad * 4 + r) * 72 + nt * 16 + lq] =
                        (u16)((__float_as_uint(acc[nt][r] * scl) + 0x8000u) >> 16);

            const int row = lane >> 2;
            const int ch  = (lane & 3) << 4;
            short8 v0 = *(const short8*)&bb[row * 72 + ch];       // wave-private RAW
            short8 v1 = *(const short8*)&bb[row * 72 + ch + 8];
            u16* dst = ((m == 0) ? Q : K) + ((size_t)(b * SS + s0 + w * 16 + row)) * CC + ch;
            *(short8*)dst = v0;
            *(short8*)(dst + 8) = v1;
        }
    }
}

// ---------------------------------------------------------------------------
// Kernel B: flash attention + fused out-projection.
// V14 (session best, 85.5us): R2-verified structure — zero-LDS P via
// permuted V slot order, K+V LDS double-buffer, 2 q-groups/wave, 2
// blocks/CU, setprio on MFMA clusters — plus ZV C-operand fold and
// v_cvt_pk_bf16_f32 P-pack. Closed lines (measured): 2x2 wave split
// (R5-R8: accumulator scratch demotion), V-direct-from-L2 (R4: TA
// scatter), 64q/wave (R10: 1 wave/SIMD latency-exposed), 2-tiles/barrier
// (R11: +3us). Counters at this point: DS ~57% of practical ceiling,
// MFMA 33%, VALU 38% — dependency-limited local minimum of this family.
// ---------------------------------------------------------------------------
__global__ __launch_bounds__(256, 2) void flash_kernel(
    const u16* __restrict__ Q, const u16* __restrict__ K,
    const u16* __restrict__ Vt, const float* __restrict__ ow,
    const float* __restrict__ ob, float* __restrict__ out)
{
    const int b    = blockIdx.x & 15;          // batch-major: XCD gets 2 batches
    const int q0   = (blockIdx.x >> 4) << 7;   // 128 q per block
    const int tid  = threadIdx.x;
    const int w    = tid >> 6;
    const int lane = tid & 63;
    const int lq   = lane & 15;
    const int quad = lane >> 4;

    __shared__ u16 lds_k[2][64 * 64];          // K tile [key][c], chunk-XOR swizzled
    __shared__ u16 lds_v[2][64 * 64];          // V^T tile [c][slot], key-permuted + swizzled
    __shared__ u16 lds_p[8][16 * 64];          // epilogue O bounce only

    // Q B-frags for both groups
    bf16x8 qf[2][2];
#pragma unroll
    for (int g = 0; g < 2; ++g) {
        const u16* qp = Q + ((size_t)(b * SS + q0 + g * 64 + w * 16 + lq)) * CC + quad * 8;
        qf[g][0] = *(const bf16x8*)(qp);
        qf[g][1] = *(const bf16x8*)(qp + 32);
    }

    f32x4 ot[2][4];
#pragma unroll
    for (int g = 0; g < 2; ++g)
#pragma unroll
        for (int ct = 0; ct < 4; ++ct) ot[g][ct] = (f32x4){0.f, 0.f, 0.f, 0.f};
    float lp[2][4] = {{0.f, 0.f, 0.f, 0.f}, {0.f, 0.f, 0.f, 0.f}};

    const f32x4 ZV = (f32x4){0.f, 0.f, 0.f, 0.f};   // loop-invariant MFMA C=0

    // staging: thread covers row srow, 16B K-chunks 2a, 2a+1 (XOR-swizzled);
    // V as 4x 8B pieces at permuted slots.
    const int srow = tid >> 2;
    const int a    = tid & 3;
    const u16* kg = K + ((size_t)(b * SS + srow)) * CC + a * 16;
    const u16* vg = Vt + ((size_t)(b * CC + srow)) * SS + a * 16;
    const int ssw = srow & 7;
    const int sw0 = srow * 64 + ((((a << 1)    ) ^ ssw) << 3);
    const int sw1 = srow * 64 + ((((a << 1) | 1) ^ ssw) << 3);
    // V permuted-slot write offsets: this thread holds (kc = a>>1, u = a&1),
    // pieces q=0..3 of 4 keys each -> slot chunk 4kc+q, intra-chunk offset 4u.
    const int kcs = (a >> 1) << 2;
    const int us  = (a & 1) << 2;
    const int vw0 = srow * 64 + (((kcs + 0) ^ ssw) << 3) + us;
    const int vw1 = srow * 64 + (((kcs + 1) ^ ssw) << 3) + us;
    const int vw2 = srow * 64 + (((kcs + 2) ^ ssw) << 3) + us;
    const int vw3 = srow * 64 + (((kcs + 3) ^ ssw) << 3) + us;

    {   // prologue: tile 0 -> buf 0
        short8 k0 = *(const short8*)(kg);
        short8 k1 = *(const short8*)(kg + 8);
        union { short8 v; s16x4 h[2]; } v0, v1;
        v0.v = *(const short8*)(vg);
        v1.v = *(const short8*)(vg + 8);
        *(short8*)&lds_k[0][sw0] = k0;
        *(short8*)&lds_k[0][sw1] = k1;
        *(s16x4*)&lds_v[0][vw0] = v0.h[0];
        *(s16x4*)&lds_v[0][vw1] = v0.h[1];
        *(s16x4*)&lds_v[0][vw2] = v1.h[0];
        *(s16x4*)&lds_v[0][vw3] = v1.h[1];
    }

    const int lsw = lq & 7;
    u16* pw0 = lds_p[(w << 1)];
    u16* pw1 = lds_p[(w << 1) | 1];

    for (int kt = 0; kt < 64; ++kt) {
        __syncthreads();
        const int buf = kt & 1;

        // prefetch tile kt+1 (consumed at end of body)
        const int ktn = (kt + 1) & 63;
        const u16* kgn = kg + (size_t)ktn * (64 * CC);
        const u16* vgn = vg + ktn * 64;
        short8 nk0 = *(const short8*)(kgn);
        short8 nk1 = *(const short8*)(kgn + 8);
        union { short8 v; s16x4 h[2]; } nv0, nv1;
        nv0.v = *(const short8*)(vgn);
        nv1.v = *(const short8*)(vgn + 8);

        // K frags loaded ONCE, feed both q-groups
        bf16x8 kf[2][4];
#pragma unroll
        for (int kc = 0; kc < 2; ++kc)
#pragma unroll
            for (int mt = 0; mt < 4; ++mt)
                kf[kc][mt] = *(const bf16x8*)
                    &lds_k[buf][(mt * 16 + lq) * 64 + (((kc << 2) + quad) ^ lsw) * 8];

        // S^T = K * Q^T for both groups (C=0 folded via ZV)
        f32x4 sa[2][4];
        __builtin_amdgcn_s_setprio(1);
#pragma unroll
        for (int g = 0; g < 2; ++g)
#pragma unroll
            for (int mt = 0; mt < 4; ++mt) {
                sa[g][mt] = __builtin_amdgcn_mfma_f32_16x16x32_bf16(
                    kf[0][mt], qf[g][0], ZV, 0, 0, 0);
                sa[g][mt] = __builtin_amdgcn_mfma_f32_16x16x32_bf16(
                    kf[1][mt], qf[g][1], sa[g][mt], 0, 0, 0);
            }
        __builtin_amdgcn_s_setprio(0);

        // V frags loaded ONCE (hoisted above softmax for latency cover);
        // same verified b128 pattern — elements are permuted-slot order.
        bf16x8 vf[2][4];
#pragma unroll
        for (int kc = 0; kc < 2; ++kc)
#pragma unroll
            for (int ct = 0; ct < 4; ++ct)
                vf[kc][ct] = *(const bf16x8*)
                    &lds_v[buf][(ct * 16 + lq) * 64 + (((kc << 2) + quad) ^ lsw) * 8];

        // softmax (fixed max): p = exp2(s); pack straight into PV B-frags.
        // pf[kc] element j: j<4 -> p[mt=2kc][r=j], j>=4 -> p[mt=2kc+1][r=j-4],
        // matching the permuted V slot order. Zero LDS, zero shuffles.
#pragma unroll
        for (int g = 0; g < 2; ++g) {
            union { uint32_t u[4]; bf16x8 v; } pf[2];
#pragma unroll
            for (int mt = 0; mt < 4; ++mt) {
                float p0 = __builtin_amdgcn_exp2f(sa[g][mt][0]);
                float p1 = __builtin_amdgcn_exp2f(sa[g][mt][1]);
                float p2 = __builtin_amdgcn_exp2f(sa[g][mt][2]);
                float p3 = __builtin_amdgcn_exp2f(sa[g][mt][3]);
                lp[g][0] += p0; lp[g][1] += p1; lp[g][2] += p2; lp[g][3] += p3;
                pf[mt >> 1].u[(mt & 1) * 2 + 0] = cvtpk(p0, p1);
                pf[mt >> 1].u[(mt & 1) * 2 + 1] = cvtpk(p2, p3);
            }
            // O^T += V^T * P^T
            __builtin_amdgcn_s_setprio(1);
#pragma unroll
            for (int kc = 0; kc < 2; ++kc)
#pragma unroll
                for (int ct = 0; ct < 4; ++ct)
                    ot[g][ct] = __builtin_amdgcn_mfma_f32_16x16x32_bf16(
                        vf[kc][ct], pf[kc].v, ot[g][ct], 0, 0, 0);
            __builtin_amdgcn_s_setprio(0);
        }

        // stage prefetched tile into other buffer
        u16* lkd = lds_k[buf ^ 1];
        u16* lvd = lds_v[buf ^ 1];
        *(short8*)&lkd[sw0] = nk0;
        *(short8*)&lkd[sw1] = nk1;
        *(s16x4*)&lvd[vw0] = nv0.h[0];
        *(s16x4*)&lvd[vw1] = nv0.h[1];
        *(s16x4*)&lvd[vw2] = nv1.h[0];
        *(s16x4*)&lvd[vw3] = nv1.h[1];
    }

    // ---- fused out-projection epilogue ----
    bf16x8 wf[2][4];
#pragma unroll
    for (int kc = 0; kc < 2; ++kc)
#pragma unroll
        for (int nt = 0; nt < 4; ++nt)
            wf[kc][nt] = ldw8(ow + (nt * 16 + lq) * 64 + kc * 32 + quad * 8);
    float bias[4];
#pragma unroll
    for (int nt = 0; nt < 4; ++nt) bias[nt] = ob[nt * 16 + lq];

#pragma unroll
    for (int g = 0; g < 2; ++g) {
        float l = (lp[g][0] + lp[g][1]) + (lp[g][2] + lp[g][3]);
        l += __shfl_xor(l, 16);
        l += __shfl_xor(l, 32);
        const float inv = 1.0f / l;

        u16* po = g ? pw1 : pw0;
#pragma unroll
        for (int ct = 0; ct < 4; ++ct) {
            uint2 pv;
            pv.x = pkbf(ot[g][ct][0] * inv, ot[g][ct][1] * inv);
            pv.y = pkbf(ot[g][ct][2] * inv, ot[g][ct][3] * inv);
            *(uint2*)&po[lq * 64 + (((ct * 2 + (quad >> 1)) ^ lsw) << 3) + (quad & 1) * 4] = pv;
        }
        bf16x8 oa0 = *(const bf16x8*)&po[lq * 64 + (((0 * 4 + quad) ^ lsw) << 3)];
        bf16x8 oa1 = *(const bf16x8*)&po[lq * 64 + (((1 * 4 + quad) ^ lsw) << 3)];

        f32x4 acc[4];
#pragma unroll
        for (int nt = 0; nt < 4; ++nt)
            acc[nt] = (f32x4){bias[nt], bias[nt], bias[nt], bias[nt]};
#pragma unroll
        for (int nt = 0; nt < 4; ++nt) {
            acc[nt] = __builtin_amdgcn_mfma_f32_16x16x32_bf16(oa0, wf[0][nt], acc[nt], 0, 0, 0);
            acc[nt] = __builtin_amdgcn_mfma_f32_16x16x32_bf16(oa1, wf[1][nt], acc[nt], 0, 0, 0);
        }
#pragma unroll
        for (int nt = 0; nt < 4; ++nt) {
            float* dst = out + ((size_t)(b * CC + nt * 16 + lq)) * SS
                       + q0 + g * 64 + w * 16 + quad * 4;
            *(f32x4*)dst = acc[nt];
        }
    }
}

// ---------------------------------------------------------------------------
extern "C" void kernel_launch(void* const* d_in, const int* in_sizes, int n_in,
                              void* d_out, int out_size, void* d_ws, size_t ws_size,
                              hipStream_t stream)
{
    const float* x  = (const float*)d_in[0];
    const float* qw = (const float*)d_in[1];
    const float* qb = (const float*)d_in[2];
    const float* kw = (const float*)d_in[3];
    const float* kb = (const float*)d_in[4];
    const float* vw = (const float*)d_in[5];
    const float* vb = (const float*)d_in[6];
    const float* ow = (const float*)d_in[7];
    const float* ob = (const float*)d_in[8];
    float* out = (float*)d_out;

    const size_t T = (size_t)BB * SS * CC;
    u16* Q  = (u16*)d_ws;
    u16* K  = Q + T;
    u16* VT = K + T;

    qkv_kernel<<<dim3(BB * 64), dim3(256), 0, stream>>>(x, qw, qb, kw, kb, vw, vb, Q, K, VT);
    flash_kernel<<<dim3(BB * 32), dim3(256), 0, stream>>>(Q, K, VT, ow, ob, out);
}